// Round 1
// baseline (692.791 us; speedup 1.0000x reference)
//
#include <hip/hip_runtime.h>
#include <math.h>

#define N_NODES 20000
#define N_EDGES 100000
// dims: node 64, edge 32, heads 2, out 64 -> H*D = 128 everywhere

// ---------------------------------------------------------------------------
// CSR build: count -> scan -> scatter
// ---------------------------------------------------------------------------
__global__ __launch_bounds__(256) void count_kernel(const int* __restrict__ dst,
                                                    int* __restrict__ cnt) {
    int e = blockIdx.x * 256 + threadIdx.x;
    if (e < N_EDGES) atomicAdd(&cnt[dst[e]], 1);
}

__global__ __launch_bounds__(256) void scan_kernel(const int* __restrict__ cnt,
                                                   int* __restrict__ row_ptr) {
    // single block, 256 threads, exclusive scan of cnt[N_NODES] -> row_ptr[N_NODES+1]
    __shared__ int part[256];
    const int tid = threadIdx.x;
    const int CH = (N_NODES + 255) / 256;  // 79
    const int base = tid * CH;
    int s = 0;
    for (int i = 0; i < CH; i++) {
        int idx = base + i;
        if (idx < N_NODES) s += cnt[idx];
    }
    part[tid] = s;
    __syncthreads();
    // Hillis-Steele inclusive scan over 256 partials
    for (int off = 1; off < 256; off <<= 1) {
        int v = 0;
        if (tid >= off) v = part[tid - off];
        __syncthreads();
        part[tid] += v;
        __syncthreads();
    }
    int run = part[tid] - s;  // exclusive prefix of this chunk
    for (int i = 0; i < CH; i++) {
        int idx = base + i;
        if (idx < N_NODES) {
            row_ptr[idx] = run;
            run += cnt[idx];
        }
    }
    if (tid == 255) row_ptr[N_NODES] = run;  // == N_EDGES
}

__global__ __launch_bounds__(256) void scatter_kernel(const int* __restrict__ dst,
                                                      const int* __restrict__ row_ptr,
                                                      int* __restrict__ cursor,
                                                      int* __restrict__ edge_idx) {
    int e = blockIdx.x * 256 + threadIdx.x;
    if (e < N_EDGES) {
        int d = dst[e];
        int pos = row_ptr[d] + atomicAdd(&cursor[d], 1);
        edge_idx[pos] = e;
    }
}

// ---------------------------------------------------------------------------
// node GEMM: FT[N,128] = X[N,64] @ W[64,128]; fused el/er = einsum(ft, al/ar)
// one wave per node; lane l owns cols l (head0) and 64+l (head1)
// ---------------------------------------------------------------------------
__global__ __launch_bounds__(256) void node_gemm(const float* __restrict__ X,
                                                 const float* __restrict__ W,
                                                 const float* __restrict__ al,
                                                 const float* __restrict__ ar,
                                                 float* __restrict__ FT,
                                                 float* __restrict__ EL,
                                                 float* __restrict__ ER) {
    __shared__ float WS[64 * 128];  // 32 KB
    const int tid = threadIdx.x;
    for (int i = tid; i < 64 * 128; i += 256) WS[i] = W[i];
    __syncthreads();
    const int lane = tid & 63;
    const int node = blockIdx.x * 4 + (tid >> 6);
    if (node >= N_NODES) return;

    const float al0 = al[lane], al1 = al[64 + lane];
    const float ar0 = ar[lane], ar1 = ar[64 + lane];

    float xv = X[node * 64 + lane];  // coalesced; whole row held across the wave
    float acc0 = 0.f, acc1 = 0.f;
#pragma unroll
    for (int k = 0; k < 64; k++) {
        float xk = __shfl(xv, k);
        acc0 = fmaf(xk, WS[k * 128 + lane], acc0);
        acc1 = fmaf(xk, WS[k * 128 + 64 + lane], acc1);
    }
    FT[node * 128 + lane] = acc0;
    FT[node * 128 + 64 + lane] = acc1;

    // fused attention coefficients: el[n,h] = sum_d ft[n,h,d]*al[h,d]
    float e0 = acc0 * al0, e1 = acc1 * al1;
    float f0 = acc0 * ar0, f1 = acc1 * ar1;
#pragma unroll
    for (int off = 32; off; off >>= 1) {
        e0 += __shfl_xor(e0, off);
        e1 += __shfl_xor(e1, off);
        f0 += __shfl_xor(f0, off);
        f1 += __shfl_xor(f1, off);
    }
    if (lane == 0) {
        EL[node * 2 + 0] = e0;
        EL[node * 2 + 1] = e1;
        ER[node * 2 + 0] = f0;
        ER[node * 2 + 1] = f1;
    }
}

// ---------------------------------------------------------------------------
// Wcomb[j,c] = sum_i W_e2d[i,j] * Wn[i,c]   (folds encoder_to_decoder into dec0 GEMM)
// ---------------------------------------------------------------------------
__global__ __launch_bounds__(256) void comb_kernel(const float* __restrict__ W_e2d,
                                                   const float* __restrict__ Wn,
                                                   float* __restrict__ Wcomb) {
    int idx = blockIdx.x * 256 + threadIdx.x;  // 8192 outputs
    int j = idx >> 7, c = idx & 127;
    float acc = 0.f;
#pragma unroll 8
    for (int i = 0; i < 64; i++) acc = fmaf(W_e2d[i * 64 + j], Wn[i * 128 + c], acc);
    Wcomb[idx] = acc;
}

// ---------------------------------------------------------------------------
// gather: one wave per dst node. Recomputes fe = e_row @ We on the fly,
// online-softmax over incoming edges, writes head-mean (+bias) [N,64].
// ---------------------------------------------------------------------------
__global__ __launch_bounds__(256) void gather_kernel(const float* __restrict__ FT,
                                                     const float* __restrict__ EL,
                                                     const float* __restrict__ ER,
                                                     const float* __restrict__ Efeat,  // [E,32]
                                                     const int* __restrict__ SRC,
                                                     const int* __restrict__ row_ptr,
                                                     const int* __restrict__ edge_idx,
                                                     const float* __restrict__ We,   // [32,128]
                                                     const float* __restrict__ ae,   // [2,64]
                                                     const float* __restrict__ bias, // [2,64]
                                                     float* __restrict__ OUT) {      // [N,64]
    __shared__ float WeS[32 * 128];  // 16 KB
    const int tid = threadIdx.x;
    for (int i = tid; i < 32 * 128; i += 256) WeS[i] = We[i];
    __syncthreads();
    const int lane = tid & 63;
    const int node = blockIdx.x * 4 + (tid >> 6);
    if (node >= N_NODES) return;

    const float aev0 = ae[lane], aev1 = ae[64 + lane];
    const float er0 = ER[node * 2 + 0], er1 = ER[node * 2 + 1];
    const int beg = row_ptr[node], end = row_ptr[node + 1];

    float m0 = -__builtin_inff(), m1 = -__builtin_inff();
    float l0 = 0.f, l1 = 0.f, acc0 = 0.f, acc1 = 0.f;

    for (int j = beg; j < end; j++) {
        const int eid = edge_idx[j];
        const int sn = SRC[eid];
        // edge-feature row, broadcast across wave via shfl
        float ev = Efeat[eid * 32 + (lane & 31)];
        float fe0 = 0.f, fe1 = 0.f;
#pragma unroll
        for (int k = 0; k < 32; k++) {
            float ek = __shfl(ev, k);
            fe0 = fmaf(ek, WeS[k * 128 + lane], fe0);
            fe1 = fmaf(ek, WeS[k * 128 + 64 + lane], fe1);
        }
        const float ft0 = FT[sn * 128 + lane];
        const float ft1 = FT[sn * 128 + 64 + lane];
        const float el0 = EL[sn * 2 + 0];
        const float el1 = EL[sn * 2 + 1];
        // ee[h] = sum_d fe[h,d]*ae[h,d] — butterfly so all lanes get the sum
        float r0 = fe0 * aev0, r1 = fe1 * aev1;
#pragma unroll
        for (int off = 32; off; off >>= 1) {
            r0 += __shfl_xor(r0, off);
            r1 += __shfl_xor(r1, off);
        }
        float lg0 = el0 + er0 + r0;
        lg0 = lg0 > 0.f ? lg0 : 0.2f * lg0;
        float lg1 = el1 + er1 + r1;
        lg1 = lg1 > 0.f ? lg1 : 0.2f * lg1;
        // online softmax, head 0
        float nm0 = fmaxf(m0, lg0);
        float sc0 = expf(m0 - nm0);  // exp(-inf)=0 on first edge
        float w0 = expf(lg0 - nm0);
        l0 = l0 * sc0 + w0;
        acc0 = acc0 * sc0 + w0 * (ft0 + fe0);
        m0 = nm0;
        // head 1
        float nm1 = fmaxf(m1, lg1);
        float sc1 = expf(m1 - nm1);
        float w1 = expf(lg1 - nm1);
        l1 = l1 * sc1 + w1;
        acc1 = acc1 * sc1 + w1 * (ft1 + fe1);
        m1 = nm1;
    }
    const float inv0 = l0 > 0.f ? 1.f / l0 : 0.f;  // zero-in-degree -> pure bias
    const float inv1 = l1 > 0.f ? 1.f / l1 : 0.f;
    OUT[node * 64 + lane] =
        0.5f * (acc0 * inv0 + bias[lane] + acc1 * inv1 + bias[64 + lane]);
}

// ---------------------------------------------------------------------------
extern "C" void kernel_launch(void* const* d_in, const int* in_sizes, int n_in,
                              void* d_out, int out_size, void* d_ws, size_t ws_size,
                              hipStream_t stream) {
    const float* x = (const float*)d_in[0];    // [2,20000,64]
    const float* e = (const float*)d_in[1];    // [2,100000,32]
    const int* src = (const int*)d_in[2];      // [2,100000]
    const int* dst = (const int*)d_in[3];      // [2,100000]

    // Only the LAST snapshot contributes to the output (decoded[-1]).
    const float* x1 = x + (size_t)1 * N_NODES * 64;
    const float* e1 = e + (size_t)1 * N_EDGES * 32;
    const int* src1 = src + N_EDGES;
    const int* dst1 = dst + N_EDGES;

    // Param layout: setup_inputs dict order puts W_e2d LAST (idx 28). Detect
    // defensively: if idx 16 is 64x64 (=4096) it's signature order instead.
    int we2d_idx, dec0_b, dec1_b;
    if (in_sizes[16] == 64 * 64 && in_sizes[17] == 64 * 128) {
        we2d_idx = 16; dec0_b = 17; dec1_b = 23;
    } else {
        dec0_b = 16; dec1_b = 22; we2d_idx = 28;
    }
    auto P = [&](int i) { return (const float*)d_in[i]; };

    // workspace layout (byte offsets, all 16B aligned)
    char* ws = (char*)d_ws;
    int* cnt       = (int*)(ws + 0);          // 80000 B
    int* row_ptr   = (int*)(ws + 81920);      // 80004 B
    int* cursor    = (int*)(ws + 163840);     // 80000 B
    int* edge_idx  = (int*)(ws + 245760);     // 400000 B
    float* ft      = (float*)(ws + 655360);   // 10.24 MB
    float* el      = (float*)(ws + 10895360); // 160 KB
    float* er      = (float*)(ws + 11055360); // 160 KB
    float* h_a     = (float*)(ws + 11215360); // 5.12 MB
    float* h_b     = (float*)(ws + 16335360); // 5.12 MB
    float* wcomb   = (float*)(ws + 21455360); // 32 KB
    // total ~20.5 MB

    // --- CSR build for snapshot 1 (reused by all 4 layers) ---
    hipMemsetAsync(cnt, 0, N_NODES * sizeof(int), stream);
    hipMemsetAsync(cursor, 0, N_NODES * sizeof(int), stream);
    const int EB = (N_EDGES + 255) / 256;
    count_kernel<<<EB, 256, 0, stream>>>(dst1, cnt);
    scan_kernel<<<1, 256, 0, stream>>>(cnt, row_ptr);
    scatter_kernel<<<EB, 256, 0, stream>>>(dst1, row_ptr, cursor, edge_idx);

    const int NB = N_NODES / 4;  // 5000 blocks x 4 waves

    auto run_layer = [&](const float* Xin, const float* Wn, const float* al_,
                         const float* ar_, const float* We_, const float* ae_,
                         const float* b_, float* Out) {
        node_gemm<<<NB, 256, 0, stream>>>(Xin, Wn, al_, ar_, ft, el, er);
        gather_kernel<<<NB, 256, 0, stream>>>(ft, el, er, e1, src1, row_ptr,
                                              edge_idx, We_, ae_, b_, Out);
    };

    // enc0: params 4..9 (Wn, We, al, ar, ae, b)
    run_layer(x1, P(4), P(6), P(7), P(5), P(8), P(9), h_a);
    // enc1: params 10..15
    run_layer(h_a, P(10), P(12), P(13), P(11), P(14), P(15), h_b);
    // encoder_to_decoder folded into dec0's node GEMM: Wcomb = W_e2d^T @ dec0_Wn
    comb_kernel<<<32, 256, 0, stream>>>(P(we2d_idx), P(dec0_b + 0), wcomb);
    // dec0
    run_layer(h_b, wcomb, P(dec0_b + 2), P(dec0_b + 3), P(dec0_b + 1),
              P(dec0_b + 4), P(dec0_b + 5), h_a);
    // dec1 -> final output (float32 [20000,64])
    run_layer(h_a, P(dec1_b + 0), P(dec1_b + 2), P(dec1_b + 3), P(dec1_b + 1),
              P(dec1_b + 4), P(dec1_b + 5), (float*)d_out);
}

// Round 2
// 413.593 us; speedup vs baseline: 1.6751x; 1.6751x over previous
//
#include <hip/hip_runtime.h>
#include <math.h>

#define N_NODES 20000
#define N_EDGES 100000
// dims: node 64, edge 32, heads 2, out 64 -> H*D = 128 everywhere

__device__ __forceinline__ float rl_f(float v, int l) {
    return __uint_as_float(__builtin_amdgcn_readlane(__float_as_uint(v), l));
}
__device__ __forceinline__ int rl_i(int v, int l) {
    return __builtin_amdgcn_readlane(v, l);
}
__device__ __forceinline__ float lrelu(float x) { return x > 0.f ? x : 0.2f * x; }

// ---------------------------------------------------------------------------
// CSR build: count(+pos) -> scan -> scatter   (no cursor atomics round 2)
// ---------------------------------------------------------------------------
__global__ __launch_bounds__(256) void count_kernel(const int* __restrict__ dst,
                                                    int* __restrict__ cnt,
                                                    int* __restrict__ pos) {
    int e = blockIdx.x * 256 + threadIdx.x;
    if (e < N_EDGES) pos[e] = atomicAdd(&cnt[dst[e]], 1);
}

__global__ __launch_bounds__(256) void scan_kernel(const int* __restrict__ cnt,
                                                   int* __restrict__ row_ptr) {
    __shared__ int part[256];
    const int tid = threadIdx.x;
    const int CH = (N_NODES + 255) / 256;  // 79
    const int base = tid * CH;
    int s = 0;
    for (int i = 0; i < CH; i++) {
        int idx = base + i;
        if (idx < N_NODES) s += cnt[idx];
    }
    part[tid] = s;
    __syncthreads();
    for (int off = 1; off < 256; off <<= 1) {
        int v = 0;
        if (tid >= off) v = part[tid - off];
        __syncthreads();
        part[tid] += v;
        __syncthreads();
    }
    int run = part[tid] - s;
    for (int i = 0; i < CH; i++) {
        int idx = base + i;
        if (idx < N_NODES) {
            row_ptr[idx] = run;
            run += cnt[idx];
        }
    }
    if (tid == 255) row_ptr[N_NODES] = run;
}

__global__ __launch_bounds__(256) void scatter_kernel(const int* __restrict__ dst,
                                                      const int* __restrict__ row_ptr,
                                                      const int* __restrict__ pos,
                                                      int* __restrict__ edge_idx) {
    int e = blockIdx.x * 256 + threadIdx.x;
    if (e < N_EDGES) edge_idx[row_ptr[dst[e]] + pos[e]] = e;
}

// ---------------------------------------------------------------------------
// Q[k*8 + L*2 + h] = sum_d We_L[k*128 + h*64 + d] * ae_L[h*64 + d]
// ---------------------------------------------------------------------------
__global__ __launch_bounds__(256) void q_kernel(const float* __restrict__ We0, const float* __restrict__ ae0,
                                                const float* __restrict__ We1, const float* __restrict__ ae1,
                                                const float* __restrict__ We2, const float* __restrict__ ae2,
                                                const float* __restrict__ We3, const float* __restrict__ ae3,
                                                float* __restrict__ Q) {
    const int t = threadIdx.x;  // 256 = 32 k * 8 o
    const int k = t >> 3, o = t & 7, L = o >> 1, h = o & 1;
    const float* We = (L == 0) ? We0 : (L == 1) ? We1 : (L == 2) ? We2 : We3;
    const float* ae = (L == 0) ? ae0 : (L == 1) ? ae1 : (L == 2) ? ae2 : ae3;
    float acc = 0.f;
#pragma unroll 8
    for (int d = 0; d < 64; d++) acc = fmaf(We[k * 128 + h * 64 + d], ae[h * 64 + d], acc);
    Q[t] = acc;
}

// ---------------------------------------------------------------------------
// EE[e*8+o] = Efeat[e,:] . Q[:,o]   (all 4 layers x 2 heads at once)
// ---------------------------------------------------------------------------
__global__ __launch_bounds__(256) void ee_kernel(const float* __restrict__ Efeat,
                                                 const float* __restrict__ Q,
                                                 float* __restrict__ EE) {
    __shared__ float QS[256];
    const int tid = threadIdx.x;
    QS[tid] = Q[tid];
    __syncthreads();
    const int e = blockIdx.x * 32 + (tid >> 3);
    const int o = tid & 7;
    if (e >= N_EDGES) return;
    const float4* E4 = (const float4*)(Efeat + (size_t)e * 32);
    float acc = 0.f;
#pragma unroll
    for (int k4 = 0; k4 < 8; k4++) {
        float4 v = E4[k4];
        acc = fmaf(v.x, QS[(k4 * 4 + 0) * 8 + o], acc);
        acc = fmaf(v.y, QS[(k4 * 4 + 1) * 8 + o], acc);
        acc = fmaf(v.z, QS[(k4 * 4 + 2) * 8 + o], acc);
        acc = fmaf(v.w, QS[(k4 * 4 + 3) * 8 + o], acc);
    }
    EE[e * 8 + o] = acc;
}

// ---------------------------------------------------------------------------
// Wcomb[j,c] = sum_i W_e2d[i,j] * Wn[i,c]
// ---------------------------------------------------------------------------
__global__ __launch_bounds__(256) void comb_kernel(const float* __restrict__ W_e2d,
                                                   const float* __restrict__ Wn,
                                                   float* __restrict__ Wcomb) {
    int idx = blockIdx.x * 256 + threadIdx.x;
    int j = idx >> 7, c = idx & 127;
    float acc = 0.f;
#pragma unroll 8
    for (int i = 0; i < 64; i++) acc = fmaf(W_e2d[i * 64 + j], Wn[i * 128 + c], acc);
    Wcomb[idx] = acc;
}

// ---------------------------------------------------------------------------
// node GEMM (grid-stride, one wave per node-iter):
// FT2[n*64+l] = (ft[n,h0,l], ft[n,h1,l]);  EL2/ER2[n] = attention coeffs
// ---------------------------------------------------------------------------
__global__ __launch_bounds__(256) void node_gemm(const float* __restrict__ X,
                                                 const float* __restrict__ W,
                                                 const float* __restrict__ al,
                                                 const float* __restrict__ ar,
                                                 float2* __restrict__ FT2,
                                                 float2* __restrict__ EL2,
                                                 float2* __restrict__ ER2) {
    __shared__ float4 WS4[32 * 64];  // 32 KB: {W[2k][l], W[2k][64+l], W[2k+1][l], W[2k+1][64+l]}
    const int tid = threadIdx.x;
    for (int idx = tid; idx < 32 * 64; idx += 256) {
        int k2 = idx >> 6, l = idx & 63;
        WS4[idx] = make_float4(W[(2 * k2) * 128 + l], W[(2 * k2) * 128 + 64 + l],
                               W[(2 * k2 + 1) * 128 + l], W[(2 * k2 + 1) * 128 + 64 + l]);
    }
    __syncthreads();
    const int lane = tid & 63;
    const int wave = tid >> 6;
    const float al0 = al[lane], al1 = al[64 + lane];
    const float ar0 = ar[lane], ar1 = ar[64 + lane];

    for (int node = blockIdx.x * 4 + wave; node < N_NODES; node += gridDim.x * 4) {
        float xv = X[node * 64 + lane];
        float acc0 = 0.f, acc1 = 0.f;
#pragma unroll
        for (int k2 = 0; k2 < 32; k2++) {
            float4 w4 = WS4[k2 * 64 + lane];  // ds_read_b128
            float x0 = rl_f(xv, 2 * k2);
            float x1 = rl_f(xv, 2 * k2 + 1);
            acc0 = fmaf(x0, w4.x, acc0);
            acc1 = fmaf(x0, w4.y, acc1);
            acc0 = fmaf(x1, w4.z, acc0);
            acc1 = fmaf(x1, w4.w, acc1);
        }
        FT2[node * 64 + lane] = make_float2(acc0, acc1);
        float e0 = acc0 * al0, e1 = acc1 * al1;
        float f0 = acc0 * ar0, f1 = acc1 * ar1;
#pragma unroll
        for (int off = 32; off; off >>= 1) {
            e0 += __shfl_xor(e0, off);
            e1 += __shfl_xor(e1, off);
            f0 += __shfl_xor(f0, off);
            f1 += __shfl_xor(f1, off);
        }
        if (lane == 0) {
            EL2[node] = make_float2(e0, e1);
            ER2[node] = make_float2(f0, f1);
        }
    }
}

// ---------------------------------------------------------------------------
// gather: one wave per node (grid-stride). Two-pass softmax with lane-parallel
// logits (EE precomputed); serial loop only does 3 coalesced loads + 3 FMA per
// edge; We applied once per node in the epilogue.
// ---------------------------------------------------------------------------
__global__ __launch_bounds__(256) void gather_kernel(const float2* __restrict__ FT2,
                                                     const float2* __restrict__ EL2,
                                                     const float2* __restrict__ ER2,
                                                     const float* __restrict__ Efeat,
                                                     const int* __restrict__ SRC,
                                                     const int* __restrict__ row_ptr,
                                                     const int* __restrict__ edge_idx,
                                                     const float2* __restrict__ EE2,
                                                     const int L,
                                                     const float* __restrict__ We,
                                                     const float* __restrict__ bias,
                                                     float* __restrict__ OUT) {
    __shared__ float4 WeS4[16 * 64];  // 16 KB: {We[2k][l], We[2k][64+l], We[2k+1][l], We[2k+1][64+l]}
    const int tid = threadIdx.x;
    for (int idx = tid; idx < 16 * 64; idx += 256) {
        int k2 = idx >> 6, l = idx & 63;
        WeS4[idx] = make_float4(We[(2 * k2) * 128 + l], We[(2 * k2) * 128 + 64 + l],
                                We[(2 * k2 + 1) * 128 + l], We[(2 * k2 + 1) * 128 + 64 + l]);
    }
    __syncthreads();
    const int lane = tid & 63;
    const int wave = tid >> 6;
    const float b0 = bias[lane], b1 = bias[64 + lane];
    const float NEG_INF = -__builtin_inff();

    for (int node = blockIdx.x * 4 + wave; node < N_NODES; node += gridDim.x * 4) {
        const int beg = row_ptr[node], end = row_ptr[node + 1];
        const int deg = end - beg;
        float2 er = ER2[node];
        float l0 = 0.f, l1 = 0.f, a0 = 0.f, a1 = 0.f, aE = 0.f;

        if (deg <= 64) {
            // --- fast path: all edges held lane-parallel ---
            int eid = 0, sn = 0;
            float lg0 = NEG_INF, lg1 = NEG_INF;
            if (lane < deg) {
                eid = edge_idx[beg + lane];
                sn = SRC[eid];
                float2 ee = EE2[eid * 4 + L];
                float2 el = EL2[sn];
                lg0 = lrelu(el.x + er.x + ee.x);
                lg1 = lrelu(el.y + er.y + ee.y);
            }
            float m0 = lg0, m1 = lg1;
#pragma unroll
            for (int off = 32; off; off >>= 1) {
                m0 = fmaxf(m0, __shfl_xor(m0, off));
                m1 = fmaxf(m1, __shfl_xor(m1, off));
            }
            float w0 = (lane < deg) ? __expf(lg0 - m0) : 0.f;
            float w1 = (lane < deg) ? __expf(lg1 - m1) : 0.f;
            l0 = w0;
            l1 = w1;
#pragma unroll
            for (int off = 32; off; off >>= 1) {
                l0 += __shfl_xor(l0, off);
                l1 += __shfl_xor(l1, off);
            }
            for (int t = 0; t < deg; t++) {
                int st = rl_i(sn, t);
                int et = rl_i(eid, t);
                float w0t = rl_f(w0, t);
                float w1t = rl_f(w1, t);
                float2 f = FT2[st * 64 + lane];
                a0 = fmaf(w0t, f.x, a0);
                a1 = fmaf(w1t, f.y, a1);
                float wEt = (lane < 32) ? w0t : w1t;
                aE = fmaf(wEt, Efeat[et * 32 + (lane & 31)], aE);
            }
        } else {
            // --- general path: chunked two-pass ---
            float m0 = NEG_INF, m1 = NEG_INF;
            for (int c = beg; c < end; c += 64) {
                int j = c + lane;
                float lg0 = NEG_INF, lg1 = NEG_INF;
                if (j < end) {
                    int eid = edge_idx[j];
                    int sn = SRC[eid];
                    float2 ee = EE2[eid * 4 + L];
                    float2 el = EL2[sn];
                    lg0 = lrelu(el.x + er.x + ee.x);
                    lg1 = lrelu(el.y + er.y + ee.y);
                }
#pragma unroll
                for (int off = 32; off; off >>= 1) {
                    lg0 = fmaxf(lg0, __shfl_xor(lg0, off));
                    lg1 = fmaxf(lg1, __shfl_xor(lg1, off));
                }
                m0 = fmaxf(m0, lg0);
                m1 = fmaxf(m1, lg1);
            }
            for (int c = beg; c < end; c += 64) {
                int j = c + lane;
                int eid = 0, sn = 0;
                float lg0 = NEG_INF, lg1 = NEG_INF;
                if (j < end) {
                    eid = edge_idx[j];
                    sn = SRC[eid];
                    float2 ee = EE2[eid * 4 + L];
                    float2 el = EL2[sn];
                    lg0 = lrelu(el.x + er.x + ee.x);
                    lg1 = lrelu(el.y + er.y + ee.y);
                }
                float w0 = (j < end) ? __expf(lg0 - m0) : 0.f;
                float w1 = (j < end) ? __expf(lg1 - m1) : 0.f;
                float s0 = w0, s1 = w1;
#pragma unroll
                for (int off = 32; off; off >>= 1) {
                    s0 += __shfl_xor(s0, off);
                    s1 += __shfl_xor(s1, off);
                }
                l0 += s0;
                l1 += s1;
                int nch = (end - c) < 64 ? (end - c) : 64;
                for (int t = 0; t < nch; t++) {
                    int st = rl_i(sn, t);
                    int et = rl_i(eid, t);
                    float w0t = rl_f(w0, t);
                    float w1t = rl_f(w1, t);
                    float2 f = FT2[st * 64 + lane];
                    a0 = fmaf(w0t, f.x, a0);
                    a1 = fmaf(w1t, f.y, a1);
                    float wEt = (lane < 32) ? w0t : w1t;
                    aE = fmaf(wEt, Efeat[et * 32 + (lane & 31)], aE);
                }
            }
        }

        // --- epilogue: fe contribution = (sum_e a_e * Efeat_e) @ We ---
        float r0 = 0.f, r1 = 0.f;
#pragma unroll
        for (int k2 = 0; k2 < 16; k2++) {
            float4 w4 = WeS4[k2 * 64 + lane];
            float ea0 = rl_f(aE, 2 * k2);
            float ea1 = rl_f(aE, 2 * k2 + 1);
            float eb0 = rl_f(aE, 32 + 2 * k2);
            float eb1 = rl_f(aE, 32 + 2 * k2 + 1);
            r0 = fmaf(ea0, w4.x, r0);
            r1 = fmaf(eb0, w4.y, r1);
            r0 = fmaf(ea1, w4.z, r0);
            r1 = fmaf(eb1, w4.w, r1);
        }
        const float inv0 = l0 > 0.f ? 1.f / l0 : 0.f;
        const float inv1 = l1 > 0.f ? 1.f / l1 : 0.f;
        OUT[node * 64 + lane] = 0.5f * ((a0 + r0) * inv0 + b0 + (a1 + r1) * inv1 + b1);
    }
}

// ---------------------------------------------------------------------------
extern "C" void kernel_launch(void* const* d_in, const int* in_sizes, int n_in,
                              void* d_out, int out_size, void* d_ws, size_t ws_size,
                              hipStream_t stream) {
    const float* x = (const float*)d_in[0];
    const float* e = (const float*)d_in[1];
    const int* src = (const int*)d_in[2];
    const int* dst = (const int*)d_in[3];

    // Only the LAST snapshot contributes to the output (decoded[-1]).
    const float* x1 = x + (size_t)1 * N_NODES * 64;
    const float* e1 = e + (size_t)1 * N_EDGES * 32;
    const int* src1 = src + N_EDGES;
    const int* dst1 = dst + N_EDGES;

    int we2d_idx, dec0_b, dec1_b;
    if (in_sizes[16] == 64 * 64 && in_sizes[17] == 64 * 128) {
        we2d_idx = 16; dec0_b = 17; dec1_b = 23;
    } else {
        dec0_b = 16; dec1_b = 22; we2d_idx = 28;
    }
    auto P = [&](int i) { return (const float*)d_in[i]; };

    // workspace layout (bytes)
    char* ws = (char*)d_ws;
    int* cnt      = (int*)(ws + 0);          //    80,000
    int* row_ptr  = (int*)(ws + 80000);      //    80,004
    int* pos      = (int*)(ws + 160064);     //   400,000
    int* edge_idx = (int*)(ws + 560064);     //   400,000
    float* q      = (float*)(ws + 960064);   //     1,024
    float* ee_all = (float*)(ws + 961088);   // 3,200,000
    float* ft     = (float*)(ws + 4161088);  // 10,240,000
    float* el     = (float*)(ws + 14401088); //   160,000
    float* er     = (float*)(ws + 14561088); //   160,000
    float* h      = (float*)(ws + 14721088); // 5,120,000
    float* wcomb  = (float*)(ws + 19841088); //    32,768
    // total 19,873,856 B (< previous 21.5 MB footprint that fit)

    hipMemsetAsync(cnt, 0, N_NODES * sizeof(int), stream);
    const int EB = (N_EDGES + 255) / 256;
    count_kernel<<<EB, 256, 0, stream>>>(dst1, cnt, pos);
    scan_kernel<<<1, 256, 0, stream>>>(cnt, row_ptr);
    scatter_kernel<<<EB, 256, 0, stream>>>(dst1, row_ptr, pos, edge_idx);

    // Per-edge attention pre-reductions for all 4 layers at once
    q_kernel<<<1, 256, 0, stream>>>(P(5), P(8), P(11), P(14),
                                    P(dec0_b + 1), P(dec0_b + 4),
                                    P(dec1_b + 1), P(dec1_b + 4), q);
    ee_kernel<<<(N_EDGES + 31) / 32, 256, 0, stream>>>(e1, q, ee_all);
    comb_kernel<<<32, 256, 0, stream>>>(P(we2d_idx), P(dec0_b + 0), wcomb);

    const int NB = 1280;  // grid-stride: 5 blocks/CU

    auto run_layer = [&](const float* Xin, const float* Wn, const float* al_,
                         const float* ar_, const float* We_, const float* b_,
                         int L, float* Out) {
        node_gemm<<<NB, 256, 0, stream>>>(Xin, Wn, al_, ar_, (float2*)ft,
                                          (float2*)el, (float2*)er);
        gather_kernel<<<NB, 256, 0, stream>>>((const float2*)ft, (const float2*)el,
                                              (const float2*)er, e1, src1, row_ptr,
                                              edge_idx, (const float2*)ee_all, L,
                                              We_, b_, Out);
    };

    // enc0 (in: x1), enc1, dec0 (W_e2d folded), dec1 -> d_out. h reused in-place:
    // node_gemm fully consumes its input before gather overwrites it.
    run_layer(x1, P(4), P(6), P(7), P(5), P(9), 0, h);
    run_layer(h, P(10), P(12), P(13), P(11), P(15), 1, h);
    run_layer(h, wcomb, P(dec0_b + 2), P(dec0_b + 3), P(dec0_b + 1), P(dec0_b + 5), 2, h);
    run_layer(h, P(dec1_b + 0), P(dec1_b + 2), P(dec1_b + 3), P(dec1_b + 1),
              P(dec1_b + 5), 3, (float*)d_out);
}